// Round 2
// baseline (14919.099 us; speedup 1.0000x reference)
//
#include <hip/hip_runtime.h>
#include <math.h>

#define NN      8000
#define PP      32
#define EG      128000
#define ES_TOT  131072     // P * 4096
#define ES_P    4096       // edges per pathway
#define DI      16
#define DD      128
#define KK1     6400
#define KK2     5120
#define KK3     4096
#define CH_P    8                    // pathways per chunk
#define NCH     (PP / CH_P)          // 4 chunks
#define CH_N    (CH_P * NN)          // 64000 nodes per chunk
#define CH_E    (CH_P * ES_P)        // 32768 edges per chunk

static __device__ __forceinline__ unsigned fkey(float f) {
    unsigned u = __float_as_uint(f);
    return (u & 0x80000000u) ? ~u : (u | 0x80000000u);
}

__global__ void k_fill(float* p, float v, int n) {
    int i = blockIdx.x * 256 + threadIdx.x;
    if (i < n) p[i] = v;
}

// deg[dst[e]-nbase] += w[e] (w==null -> 1)
__global__ void k_deg(const int* __restrict__ dst, const float* __restrict__ w,
                      float* __restrict__ deg, int ne, int nbase) {
    int e = blockIdx.x * 256 + threadIdx.x;
    if (e >= ne) return;
    float we = w ? w[e] : 1.0f;
    if (we != 0.0f) atomicAdd(&deg[dst[e] - nbase], we);
}

// agg[(dst[e]-nbase)*Dd + d] += x[srow*Dd + d] * w[e];  Dd=1<<shift
// srow = xModN ? (src[e] % NN) : (src[e] - nbase)
__global__ void k_agg(const int* __restrict__ src, const int* __restrict__ dst,
                      const float* __restrict__ x, const float* __restrict__ w,
                      float* __restrict__ agg, int ne, int shift, int xModN, int nbase) {
    long long idx = (long long)blockIdx.x * 256 + threadIdx.x;
    int e = (int)(idx >> shift);
    if (e >= ne) return;
    int Dd = 1 << shift;
    int d = (int)idx & (Dd - 1);
    float we = w ? w[e] : 1.0f;
    if (we == 0.0f) return;
    int s = src[e];
    s = xModN ? (s % NN) : (s - nbase);
    atomicAdd(&agg[(long long)(dst[e] - nbase) * Dd + d], x[(long long)s * Dd + d] * we);
}

// y = tanh( (agg/deg) @ Wl + bl + h @ Wr ), K=16, one thread per output
__global__ __launch_bounds__(256) void k_sage16(
    const float* __restrict__ h, const float* __restrict__ agg, const float* __restrict__ deg,
    const float* __restrict__ Wl, const float* __restrict__ Wr, const float* __restrict__ bl,
    float* __restrict__ y, int nrows)
{
    __shared__ float WlS[16][128], WrS[16][128];
    int tid = threadIdx.x;
    for (int i = tid; i < 16 * 128; i += 256) {
        WlS[i >> 7][i & 127] = Wl[i];
        WrS[i >> 7][i & 127] = Wr[i];
    }
    __syncthreads();
    long long o = (long long)blockIdx.x * 256 + tid;
    int row = (int)(o >> 7);
    if (row >= nrows) return;
    int d = (int)o & 127;
    float invd = 1.0f / fmaxf(deg[row], 1.0f);
    float s = bl[d];
    #pragma unroll
    for (int k = 0; k < 16; ++k)
        s += agg[row * 16 + k] * invd * WlS[k][d] + h[row * 16 + k] * WrS[k][d];
    y[(long long)row * 128 + d] = tanhf(s);
}

// y = tanh( (agg/deg) @ Wl + bl + x @ Wr ), combined K=256 GEMM.
// BM=32 rows, BN=128, BK=32. xModN -> x row = global row % NN (tiled stage-1 input).
__global__ __launch_bounds__(256) void k_sage128(
    const float* __restrict__ x, const float* __restrict__ agg, const float* __restrict__ deg,
    const float* __restrict__ Wl, const float* __restrict__ Wr, const float* __restrict__ bl,
    float* __restrict__ y, int nrows, int xModN)
{
    __shared__ float Ws[32][128];
    __shared__ float Is[32][40];   // 40-float stride: 160B rows keep float4 reads 16B-aligned
    __shared__ float degS[32];
    int tid = threadIdx.x;
    int row0 = blockIdx.x * 32;
    if (tid < 32) {
        int r = row0 + tid;
        float dg = (r < nrows) ? deg[r] : 1.0f;
        degS[tid] = 1.0f / fmaxf(dg, 1.0f);
    }
    int tx = tid & 31;   // d0 = tx*4
    int ty = tid >> 5;   // r0 = ty*4
    float acc[4][4] = {};
    for (int kb = 0; kb < 8; ++kb) {
        __syncthreads();
        #pragma unroll
        for (int i = 0; i < 16; ++i) {
            int idx = i * 256 + tid;
            int kk = idx >> 7, dd = idx & 127;
            int k = kb * 32 + kk;
            Ws[kk][dd] = (k < 128) ? Wl[k * 128 + dd] : Wr[(k - 128) * 128 + dd];
        }
        {
            int kk = tid & 31;
            int rb = tid >> 5;
            #pragma unroll
            for (int i = 0; i < 4; ++i) {
                int r = rb + i * 8;
                int row = row0 + r;
                int k = kb * 32 + kk;
                float v = 0.0f;
                if (row < nrows) {
                    if (k < 128) v = agg[(long long)row * 128 + k] * degS[r];
                    else {
                        int xr = xModN ? (row % NN) : row;
                        v = x[(long long)xr * 128 + (k - 128)];
                    }
                }
                Is[kk][r] = v;
            }
        }
        __syncthreads();
        #pragma unroll
        for (int kk = 0; kk < 32; ++kk) {
            float4 iv = *reinterpret_cast<const float4*>(&Is[kk][ty * 4]);
            float4 wv = *reinterpret_cast<const float4*>(&Ws[kk][tx * 4]);
            float ia[4] = {iv.x, iv.y, iv.z, iv.w};
            float wa[4] = {wv.x, wv.y, wv.z, wv.w};
            #pragma unroll
            for (int i = 0; i < 4; ++i)
                #pragma unroll
                for (int j = 0; j < 4; ++j)
                    acc[i][j] += ia[i] * wa[j];
        }
    }
    #pragma unroll
    for (int i = 0; i < 4; ++i) {
        int row = row0 + ty * 4 + i;
        if (row >= nrows) continue;
        #pragma unroll
        for (int j = 0; j < 4; ++j) {
            int d = tx * 4 + j;
            y[(long long)row * 128 + d] = tanhf(acc[i][j] + bl[d]);
        }
    }
}

// GlobalAttention readout: one block per graph (nodes=NN). mask==null -> all alive.
__global__ __launch_bounds__(256) void k_readout(
    const float* __restrict__ xbase, const float* __restrict__ mask,
    const float* __restrict__ gw, const float* __restrict__ gbp, int gi,
    float* __restrict__ outp, int outStride, int nodes)
{
    __shared__ float g[NN];
    __shared__ float red[256];
    __shared__ float gwS[128];
    int p = blockIdx.x, tid = threadIdx.x;
    const float* x = xbase + (long long)p * nodes * 128;
    const float* m = mask ? mask + (long long)p * nodes : nullptr;
    float* o = outp + (long long)p * outStride;
    if (tid < 128) gwS[tid] = gw[tid];
    float gb = gbp[gi];
    __syncthreads();
    float lmax = -INFINITY;
    for (int n = tid; n < nodes; n += 256) {
        float val;
        if (m && m[n] < 0.5f) val = -INFINITY;
        else {
            const float4* xr = reinterpret_cast<const float4*>(x + (long long)n * 128);
            float dot = 0.0f;
            #pragma unroll
            for (int k = 0; k < 32; ++k) {
                float4 v = xr[k];
                dot += v.x * gwS[4*k] + v.y * gwS[4*k+1] + v.z * gwS[4*k+2] + v.w * gwS[4*k+3];
            }
            val = dot + gb;
        }
        g[n] = val;
        lmax = fmaxf(lmax, val);
    }
    red[tid] = lmax; __syncthreads();
    for (int s = 128; s > 0; s >>= 1) { if (tid < s) red[tid] = fmaxf(red[tid], red[tid + s]); __syncthreads(); }
    float mx = red[0]; __syncthreads();
    float lsum = 0.0f;
    for (int n = tid; n < nodes; n += 256) {
        float e = expf(g[n] - mx);
        g[n] = e; lsum += e;
    }
    red[tid] = lsum; __syncthreads();
    for (int s = 128; s > 0; s >>= 1) { if (tid < s) red[tid] += red[tid + s]; __syncthreads(); }
    float inv = 1.0f / red[0];
    __syncthreads();
    int d = tid & 127, half = tid >> 7;
    float acc = 0.0f;
    for (int n = half; n < nodes; n += 2)
        acc += g[n] * x[(long long)n * 128 + d];
    red[tid] = acc; __syncthreads();
    if (tid < 128) o[d] = (red[d] + red[d + 128]) * inv;
}

__global__ void k_colsum(const float* __restrict__ x, float* __restrict__ musum, int nrows) {
    int d = threadIdx.x;                  // 128 threads
    int r0 = blockIdx.x * 64;
    int r1 = min(r0 + 64, nrows);
    float s = 0.0f;
    for (int r = r0; r < r1; ++r) s += x[(long long)r * 128 + d];
    atomicAdd(&musum[d], s);
}

__global__ void k_colvar(const float* __restrict__ x, const float* __restrict__ musum,
                         const float* __restrict__ ms, float* __restrict__ varsum, int nrows) {
    int d = threadIdx.x;
    float c = (musum[d] / (float)nrows) * ms[d];
    int r0 = blockIdx.x * 64;
    int r1 = min(r0 + 64, nrows);
    float s = 0.0f;
    for (int r = r0; r < r1; ++r) { float o = x[(long long)r * 128 + d] - c; s += o * o; }
    atomicAdd(&varsum[d], s);
}

__global__ void k_gnorm_apply(const float* __restrict__ x, float* __restrict__ y,
                              const float* __restrict__ musum, const float* __restrict__ varsum,
                              const float* __restrict__ w, const float* __restrict__ b,
                              const float* __restrict__ ms, int nrows) {
    long long i = (long long)blockIdx.x * 256 + threadIdx.x;
    if (i >= (long long)nrows * 128) return;
    int d = (int)(i & 127);
    float mu = musum[d] / (float)nrows;
    float var = varsum[d] / (float)nrows;
    float o = x[i] - mu * ms[d];
    y[i] = w[d] * o * rsqrtf(var + 1e-5f) + b[d];
}

// t[i] = dot(X[i], wv)
__global__ __launch_bounds__(256) void k_dotvec(const float* __restrict__ X,
                                                const float* __restrict__ wv,
                                                float* __restrict__ t, int nrows) {
    __shared__ float wS[128];
    if (threadIdx.x < 128) wS[threadIdx.x] = wv[threadIdx.x];
    __syncthreads();
    int i = blockIdx.x * 256 + threadIdx.x;
    if (i >= nrows) return;
    const float4* xr = reinterpret_cast<const float4*>(X + (long long)i * 128);
    float s = 0.0f;
    #pragma unroll
    for (int k = 0; k < 32; ++k) {
        float4 v = xr[k];
        s += v.x * wS[4*k] + v.y * wS[4*k+1] + v.z * wS[4*k+2] + v.w * wS[4*k+3];
    }
    t[i] = s;
}

// sagg[sdst[e]-nbase] += t[ssrc[e]-nbase] * eal[e]
__global__ void k_scoreagg(const int* __restrict__ ssrc, const int* __restrict__ sdst,
                           const float* __restrict__ t, const float* __restrict__ eal,
                           float* __restrict__ sagg, int ne, int nbase) {
    int e = blockIdx.x * 256 + threadIdx.x;
    if (e >= ne) return;
    float w = eal[e];
    if (w != 0.0f) atomicAdd(&sagg[sdst[e] - nbase], t[ssrc[e] - nbase] * w);
}

// score[i] = sagg[i] + brel + dot(X[i], wroot)   (in place on sagg)
__global__ __launch_bounds__(256) void k_score(const float* __restrict__ X,
                                               const float* __restrict__ wroot,
                                               float* __restrict__ sagg,
                                               const float* __restrict__ brelp, int bi, int nrows) {
    __shared__ float wS[128];
    if (threadIdx.x < 128) wS[threadIdx.x] = wroot[threadIdx.x];
    __syncthreads();
    int i = blockIdx.x * 256 + threadIdx.x;
    if (i >= nrows) return;
    const float4* xr = reinterpret_cast<const float4*>(X + (long long)i * 128);
    float s = sagg[i] + brelp[bi];
    #pragma unroll
    for (int k = 0; k < 32; ++k) {
        float4 v = xr[k];
        s += v.x * wS[4*k] + v.y * wS[4*k+1] + v.z * wS[4*k+2] + v.w * wS[4*k+3];
    }
    sagg[i] = s;
}

// per-pathway top-k: select k largest (ties -> lowest index), update nalive in place
__global__ __launch_bounds__(256) void k_topk(const float* __restrict__ score,
                                              float* __restrict__ nalive, int k) {
    __shared__ unsigned keys[NN];
    __shared__ int red[256];
    __shared__ int chunkcnt[256];
    int p = blockIdx.x, tid = threadIdx.x;
    const float* sc = score + (long long)p * NN;
    float* na = nalive + (long long)p * NN;
    for (int n = tid; n < NN; n += 256)
        keys[n] = (na[n] > 0.5f) ? fkey(sc[n]) : 0u;
    __syncthreads();
    unsigned lo = 0u, hi = 0xFFFFFFFFu;
    while (lo < hi) {
        unsigned mid = (unsigned)(((unsigned long long)lo + (unsigned long long)hi + 1ull) >> 1);
        int c = 0;
        for (int n = tid; n < NN; n += 256) c += (keys[n] >= mid) ? 1 : 0;
        red[tid] = c; __syncthreads();
        for (int s = 128; s > 0; s >>= 1) { if (tid < s) red[tid] += red[tid + s]; __syncthreads(); }
        int total = red[0]; __syncthreads();
        if (total >= k) lo = mid; else hi = mid - 1;
    }
    unsigned V = lo;
    int cg = 0;
    for (int n = tid; n < NN; n += 256) cg += (keys[n] > V) ? 1 : 0;
    red[tid] = cg; __syncthreads();
    for (int s = 128; s > 0; s >>= 1) { if (tid < s) red[tid] += red[tid + s]; __syncthreads(); }
    int seleq = k - red[0]; __syncthreads();
    int c0 = tid * 32, c1 = min(c0 + 32, NN);
    int ceq = 0;
    for (int n = c0; n < c1; ++n) ceq += (keys[n] == V) ? 1 : 0;
    chunkcnt[tid] = ceq; __syncthreads();
    if (tid == 0) {
        int s = 0;
        for (int i = 0; i < 256; ++i) { int c = chunkcnt[i]; chunkcnt[i] = s; s += c; }
    }
    __syncthreads();
    int rank = chunkcnt[tid];
    for (int n = c0; n < c1; ++n) {
        unsigned kk = keys[n];
        bool sel = (kk > V) || (kk == V && rank < seleq);
        if (kk == V) rank++;
        na[n] = sel ? 1.0f : 0.0f;
    }
}

// X[i][d] = nalive[i] ? X[i][d] * tanh(score[i]) : 0
__global__ void k_maskapply(float* __restrict__ X, const float* __restrict__ score,
                            const float* __restrict__ nalive, long long total) {
    long long i = (long long)blockIdx.x * 256 + threadIdx.x;
    if (i >= total) return;
    long long row = i >> 7;
    float f = (nalive[row] > 0.5f) ? tanhf(score[row]) : 0.0f;
    X[i] *= f;
}

__global__ void k_ealive(const int* __restrict__ ssrc, const int* __restrict__ sdst,
                         const float* __restrict__ nalive, float* __restrict__ eal,
                         int ne, int nbase) {
    int e = blockIdx.x * 256 + threadIdx.x;
    if (e >= ne) return;
    if (nalive[ssrc[e] - nbase] < 0.5f || nalive[sdst[e] - nbase] < 0.5f) eal[e] = 0.0f;
}

__global__ __launch_bounds__(64) void k_head(
    const float* __restrict__ ro, const float* __restrict__ lin_w, const float* __restrict__ lin_b,
    const float* __restrict__ m1w, const float* __restrict__ m1b,
    const float* __restrict__ m2w, const float* __restrict__ m2b,
    const float* __restrict__ m3w, const float* __restrict__ m3b, float* __restrict__ out)
{
    __shared__ float v[33], h1[48], h2[16];
    int t = threadIdx.x;
    if (t < 33) {
        float s = lin_b[0];
        for (int k = 0; k < 384; ++k) s += ro[t * 384 + k] * lin_w[k];
        v[t] = tanhf(s);
    }
    __syncthreads();
    if (t < 48) {
        float s = m1b[t];
        for (int i = 0; i < 33; ++i) s += v[i] * m1w[i * 48 + t];
        h1[t] = tanhf(s);
    }
    __syncthreads();
    if (t < 16) {
        float s = m2b[t];
        for (int i = 0; i < 48; ++i) s += h1[i] * m2w[i * 16 + t];
        h2[t] = tanhf(s);
    }
    __syncthreads();
    if (t == 0) {
        float s = m3b[0];
        for (int i = 0; i < 16; ++i) s += h2[i] * m3w[i];
        float s1 = 1.0f / (1.0f + expf(-s));
        out[0] = 1.0f / (1.0f + expf(-s1));
    }
}

static inline int cdiv(long long a, long long b) { return (int)((a + b - 1) / b); }

extern "C" void kernel_launch(void* const* d_in, const int* in_sizes, int n_in,
                              void* d_out, int out_size, void* d_ws, size_t ws_size,
                              hipStream_t stream)
{
    (void)in_sizes; (void)n_in; (void)out_size; (void)ws_size;
    const float* h     = (const float*)d_in[0];
    const int*   eidx  = (const int*)d_in[1];
    const int*   seidx = (const int*)d_in[2];
    const float* Wl_a  = (const float*)d_in[3];
    const float* Wr_a  = (const float*)d_in[4];
    const float* bl_a  = (const float*)d_in[5];
    const float* Wl_s  = (const float*)d_in[6];
    const float* Wr_s  = (const float*)d_in[7];
    const float* bl_s  = (const float*)d_in[8];
    const float* gate_w = (const float*)d_in[9];
    const float* gate_b = (const float*)d_in[10];
    const float* p_wrel = (const float*)d_in[11];
    const float* p_brel = (const float*)d_in[12];
    const float* p_wroot= (const float*)d_in[13];
    const float* nw    = (const float*)d_in[14];
    const float* nb    = (const float*)d_in[15];
    const float* nms   = (const float*)d_in[16];
    const float* lin_w = (const float*)d_in[17];
    const float* lin_b = (const float*)d_in[18];
    const float* m1w   = (const float*)d_in[19];
    const float* m1b   = (const float*)d_in[20];
    const float* m2w   = (const float*)d_in[21];
    const float* m2b   = (const float*)d_in[22];
    const float* m3w   = (const float*)d_in[23];
    const float* m3b   = (const float*)d_in[24];
    float* out = (float*)d_out;

    const int* esrc = eidx;
    const int* edst = eidx + EG;

    float* W = (float*)d_ws;
    size_t off = 0;
    auto alloc = [&](size_t nf) { float* p = W + off; off += (nf + 63) & ~(size_t)63; return p; };
    float* Xc    = alloc((size_t)CH_N * DD);   // stage-2 chunk features
    float* AGGc  = alloc((size_t)CH_N * DD);   // stage-2 chunk aggregate
    float* xa    = alloc((size_t)NN * DD);
    float* xb    = alloc((size_t)NN * DD);
    float* agg1  = alloc((size_t)NN * DD);
    float* deg1  = alloc(NN);
    float* deg2  = alloc(CH_N);
    float* tbuf  = alloc(CH_N);
    float* sagg  = alloc(CH_N);
    float* nal   = alloc(CH_N);
    float* eal   = alloc(CH_E);
    float* ro    = alloc(33 * 384);
    float* musum = alloc(128);
    float* varsum= alloc(128);
    // total ~80 MB — safe against ws_size

    // ================= stage 1 =================
    k_fill<<<cdiv(NN,256),256,0,stream>>>(deg1, 1.0f, NN);
    k_deg<<<cdiv(EG,256),256,0,stream>>>(edst, (const float*)nullptr, deg1, EG, 0);

    // layer a (DIN=16): agg init = h (self loop), then edges
    hipMemcpyAsync(agg1, h, (size_t)NN * DI * sizeof(float), hipMemcpyDeviceToDevice, stream);
    k_agg<<<cdiv((long long)EG*DI,256),256,0,stream>>>(esrc, edst, h, (const float*)nullptr, agg1, EG, 4, 0, 0);
    k_sage16<<<cdiv((long long)NN*DD,256),256,0,stream>>>(h, agg1, deg1, Wl_a, Wr_a, bl_a, xa, NN);
    k_readout<<<1,256,0,stream>>>(xa, (const float*)nullptr, gate_w + 0*DD, gate_b, 0, ro + 0, 384, NN);

    // gnorm 1: xa -> xb
    hipMemsetAsync(musum, 0, 128*sizeof(float), stream);
    hipMemsetAsync(varsum, 0, 128*sizeof(float), stream);
    k_colsum<<<cdiv(NN,64),128,0,stream>>>(xa, musum, NN);
    k_colvar<<<cdiv(NN,64),128,0,stream>>>(xa, musum, nms, varsum, NN);
    k_gnorm_apply<<<cdiv((long long)NN*DD,256),256,0,stream>>>(xa, xb, musum, varsum, nw, nb, nms, NN);

    // layer b (conv_b = idx 0)
    hipMemcpyAsync(agg1, xb, (size_t)NN * DD * sizeof(float), hipMemcpyDeviceToDevice, stream);
    k_agg<<<cdiv((long long)EG*DD,256),256,0,stream>>>(esrc, edst, xb, (const float*)nullptr, agg1, EG, 7, 0, 0);
    k_sage128<<<cdiv(NN,32),256,0,stream>>>(xb, agg1, deg1, Wl_s + 0*16384, Wr_s + 0*16384, bl_s + 0*128, xa, NN, 0);
    k_readout<<<1,256,0,stream>>>(xa, (const float*)nullptr, gate_w + 1*DD, gate_b, 1, ro + 128, 384, NN);

    // gnorm 2: xa -> xb
    hipMemsetAsync(musum, 0, 128*sizeof(float), stream);
    hipMemsetAsync(varsum, 0, 128*sizeof(float), stream);
    k_colsum<<<cdiv(NN,64),128,0,stream>>>(xa, musum, NN);
    k_colvar<<<cdiv(NN,64),128,0,stream>>>(xa, musum, nms, varsum, NN);
    k_gnorm_apply<<<cdiv((long long)NN*DD,256),256,0,stream>>>(xa, xb, musum, varsum, nw, nb, nms, NN);

    // layer c (conv_c = idx 1) -> xa = x_c
    hipMemcpyAsync(agg1, xb, (size_t)NN * DD * sizeof(float), hipMemcpyDeviceToDevice, stream);
    k_agg<<<cdiv((long long)EG*DD,256),256,0,stream>>>(esrc, edst, xb, (const float*)nullptr, agg1, EG, 7, 0, 0);
    k_sage128<<<cdiv(NN,32),256,0,stream>>>(xb, agg1, deg1, Wl_s + 1*16384, Wr_s + 1*16384, bl_s + 1*128, xa, NN, 0);
    k_readout<<<1,256,0,stream>>>(xa, (const float*)nullptr, gate_w + 2*DD, gate_b, 2, ro + 256, 384, NN);

    // ================= stage 2 (chunked over pathways) =================
    for (int c = 0; c < NCH; ++c) {
        const int* ssrc = seidx + (size_t)c * CH_E;
        const int* sdst = seidx + ES_TOT + (size_t)c * CH_E;
        int nbase = c * CH_N;

        k_fill<<<cdiv(CH_N,256),256,0,stream>>>(nal, 1.0f, CH_N);
        k_fill<<<cdiv(CH_E,256),256,0,stream>>>(eal, 1.0f, CH_E);

        for (int layer = 0; layer < 3; ++layer) {
            const float* Wl = Wl_s + (2 + layer) * 16384;
            const float* Wr = Wr_s + (2 + layer) * 16384;
            const float* bl = bl_s + (2 + layer) * 128;
            int kkeep = (layer == 0) ? KK1 : (layer == 1) ? KK2 : KK3;
            int gi = 3 + layer;

            hipMemsetAsync(AGGc, 0, (size_t)CH_N * DD * sizeof(float), stream);
            hipMemsetAsync(deg2, 0, (size_t)CH_N * sizeof(float), stream);
            k_deg<<<cdiv(CH_E,256),256,0,stream>>>(sdst, eal, deg2, CH_E, nbase);
            if (layer == 0) {
                // x input is tiled stage-1 x_c: row = src % NN
                k_agg<<<cdiv((long long)CH_E*DD,256),256,0,stream>>>(ssrc, sdst, xa, eal, AGGc, CH_E, 7, 1, nbase);
                k_sage128<<<cdiv(CH_N,32),256,0,stream>>>(xa, AGGc, deg2, Wl, Wr, bl, Xc, CH_N, 1);
            } else {
                k_agg<<<cdiv((long long)CH_E*DD,256),256,0,stream>>>(ssrc, sdst, Xc, eal, AGGc, CH_E, 7, 0, nbase);
                k_sage128<<<cdiv(CH_N,32),256,0,stream>>>(Xc, AGGc, deg2, Wl, Wr, bl, Xc, CH_N, 0);
            }

            // SAGPool: score = segsum(t[src]*w) + brel + x@wroot  (t = x@wrel)
            k_dotvec<<<cdiv(CH_N,256),256,0,stream>>>(Xc, p_wrel + layer*DD, tbuf, CH_N);
            hipMemsetAsync(sagg, 0, (size_t)CH_N * sizeof(float), stream);
            k_scoreagg<<<cdiv(CH_E,256),256,0,stream>>>(ssrc, sdst, tbuf, eal, sagg, CH_E, nbase);
            k_score<<<cdiv(CH_N,256),256,0,stream>>>(Xc, p_wroot + layer*DD, sagg, p_brel, layer, CH_N);
            k_topk<<<CH_P,256,0,stream>>>(sagg, nal, kkeep);
            k_maskapply<<<cdiv((long long)CH_N*DD,256),256,0,stream>>>(Xc, sagg, nal, (long long)CH_N * DD);
            k_ealive<<<cdiv(CH_E,256),256,0,stream>>>(ssrc, sdst, nal, eal, CH_E, nbase);

            // readout -> ro rows 1..32 (global pathway index c*CH_P + p_local)
            k_readout<<<CH_P,256,0,stream>>>(Xc, nal, gate_w + gi*DD, gate_b, gi,
                                             ro + 384 + (size_t)(c*CH_P)*384 + layer*128, 384, NN);
        }
    }

    // ================= head =================
    k_head<<<1,64,0,stream>>>(ro, lin_w, lin_b, m1w, m1b, m2w, m2b, m3w, m3b, out);
}

// Round 3
// 3913.338 us; speedup vs baseline: 3.8124x; 3.8124x over previous
//
#include <hip/hip_runtime.h>
#include <math.h>

#define NN      8000
#define PP      32
#define EG      128000
#define ES_TOT  131072     // P * 4096
#define ES_P    4096       // edges per pathway
#define DI      16
#define DD      128
#define KK1     6400
#define KK2     5120
#define KK3     4096
#define CH_P    8                    // pathways per chunk
#define NCH     (PP / CH_P)          // 4 chunks
#define CH_N    (CH_P * NN)          // 64000 nodes per chunk
#define CH_E    (CH_P * ES_P)        // 32768 edges per chunk
#define RB      64                   // rows per k_wsum block
#define BPG     (NN / RB)            // 125 blocks per graph

static __device__ __forceinline__ unsigned fkey(float f) {
    unsigned u = __float_as_uint(f);
    return (u & 0x80000000u) ? ~u : (u | 0x80000000u);
}

__global__ void k_fill(float* p, float v, int n) {
    int i = blockIdx.x * 256 + threadIdx.x;
    if (i < n) p[i] = v;
}

// deg[dst[e]-nbase] += w[e] (w==null -> 1)
__global__ void k_deg(const int* __restrict__ dst, const float* __restrict__ w,
                      float* __restrict__ deg, int ne, int nbase) {
    int e = blockIdx.x * 256 + threadIdx.x;
    if (e >= ne) return;
    float we = w ? w[e] : 1.0f;
    if (we != 0.0f) atomicAdd(&deg[dst[e] - nbase], we);
}

// agg[(dst[e]-nbase)*Dd + d] += x[srow*Dd + d] * w[e];  Dd=1<<shift
__global__ void k_agg(const int* __restrict__ src, const int* __restrict__ dst,
                      const float* __restrict__ x, const float* __restrict__ w,
                      float* __restrict__ agg, int ne, int shift, int xModN, int nbase) {
    long long idx = (long long)blockIdx.x * 256 + threadIdx.x;
    int e = (int)(idx >> shift);
    if (e >= ne) return;
    int Dd = 1 << shift;
    int d = (int)idx & (Dd - 1);
    float we = w ? w[e] : 1.0f;
    if (we == 0.0f) return;
    int s = src[e];
    s = xModN ? (s % NN) : (s - nbase);
    atomicAdd(&agg[(long long)(dst[e] - nbase) * Dd + d], x[(long long)s * Dd + d] * we);
}

// y = tanh( (agg/deg) @ Wl + bl + h @ Wr ), K=16, one thread per output
__global__ __launch_bounds__(256) void k_sage16(
    const float* __restrict__ h, const float* __restrict__ agg, const float* __restrict__ deg,
    const float* __restrict__ Wl, const float* __restrict__ Wr, const float* __restrict__ bl,
    float* __restrict__ y, int nrows)
{
    __shared__ float WlS[16][128], WrS[16][128];
    int tid = threadIdx.x;
    for (int i = tid; i < 16 * 128; i += 256) {
        WlS[i >> 7][i & 127] = Wl[i];
        WrS[i >> 7][i & 127] = Wr[i];
    }
    __syncthreads();
    long long o = (long long)blockIdx.x * 256 + tid;
    int row = (int)(o >> 7);
    if (row >= nrows) return;
    int d = (int)o & 127;
    float invd = 1.0f / fmaxf(deg[row], 1.0f);
    float s = bl[d];
    #pragma unroll
    for (int k = 0; k < 16; ++k)
        s += agg[row * 16 + k] * invd * WlS[k][d] + h[row * 16 + k] * WrS[k][d];
    y[(long long)row * 128 + d] = tanhf(s);
}

// y = tanh( (agg/deg) @ Wl + bl + x @ Wr ), combined K=256 GEMM.
__global__ __launch_bounds__(256) void k_sage128(
    const float* __restrict__ x, const float* __restrict__ agg, const float* __restrict__ deg,
    const float* __restrict__ Wl, const float* __restrict__ Wr, const float* __restrict__ bl,
    float* __restrict__ y, int nrows, int xModN)
{
    __shared__ float Ws[32][128];
    __shared__ float Is[32][40];   // 160B rows keep float4 reads 16B-aligned
    __shared__ float degS[32];
    int tid = threadIdx.x;
    int row0 = blockIdx.x * 32;
    if (tid < 32) {
        int r = row0 + tid;
        float dg = (r < nrows) ? deg[r] : 1.0f;
        degS[tid] = 1.0f / fmaxf(dg, 1.0f);
    }
    int tx = tid & 31;
    int ty = tid >> 5;
    float acc[4][4] = {};
    for (int kb = 0; kb < 8; ++kb) {
        __syncthreads();
        #pragma unroll
        for (int i = 0; i < 16; ++i) {
            int idx = i * 256 + tid;
            int kk = idx >> 7, dd = idx & 127;
            int k = kb * 32 + kk;
            Ws[kk][dd] = (k < 128) ? Wl[k * 128 + dd] : Wr[(k - 128) * 128 + dd];
        }
        {
            int kk = tid & 31;
            int rb = tid >> 5;
            #pragma unroll
            for (int i = 0; i < 4; ++i) {
                int r = rb + i * 8;
                int row = row0 + r;
                int k = kb * 32 + kk;
                float v = 0.0f;
                if (row < nrows) {
                    if (k < 128) v = agg[(long long)row * 128 + k] * degS[r];
                    else {
                        int xr = xModN ? (row % NN) : row;
                        v = x[(long long)xr * 128 + (k - 128)];
                    }
                }
                Is[kk][r] = v;
            }
        }
        __syncthreads();
        #pragma unroll
        for (int kk = 0; kk < 32; ++kk) {
            float4 iv = *reinterpret_cast<const float4*>(&Is[kk][ty * 4]);
            float4 wv = *reinterpret_cast<const float4*>(&Ws[kk][tx * 4]);
            float ia[4] = {iv.x, iv.y, iv.z, iv.w};
            float wa[4] = {wv.x, wv.y, wv.z, wv.w};
            #pragma unroll
            for (int i = 0; i < 4; ++i)
                #pragma unroll
                for (int j = 0; j < 4; ++j)
                    acc[i][j] += ia[i] * wa[j];
        }
    }
    #pragma unroll
    for (int i = 0; i < 4; ++i) {
        int row = row0 + ty * 4 + i;
        if (row >= nrows) continue;
        #pragma unroll
        for (int j = 0; j < 4; ++j) {
            int d = tx * 4 + j;
            y[(long long)row * 128 + d] = tanhf(acc[i][j] + bl[d]);
        }
    }
}

// -------- parallel GlobalAttention readout (3 kernels) --------
// gate: g[i] = mask ? dot(x[i],gw)+gb : -inf   (rows parallel)
__global__ __launch_bounds__(256) void k_gate(
    const float* __restrict__ X, const float* __restrict__ mask,
    const float* __restrict__ gw, const float* __restrict__ gbp, int gi,
    float* __restrict__ g, int nrows)
{
    __shared__ float wS[128];
    if (threadIdx.x < 128) wS[threadIdx.x] = gw[threadIdx.x];
    __syncthreads();
    int i = blockIdx.x * 256 + threadIdx.x;
    if (i >= nrows) return;
    if (mask && mask[i] < 0.5f) { g[i] = -INFINITY; return; }
    const float4* xr = reinterpret_cast<const float4*>(X + (long long)i * 128);
    float s = gbp[gi];
    #pragma unroll
    for (int k = 0; k < 32; ++k) {
        float4 v = xr[k];
        s += v.x * wS[4*k] + v.y * wS[4*k+1] + v.z * wS[4*k+2] + v.w * wS[4*k+3];
    }
    g[i] = s;
}

// per-graph softmax normalize in place: g[n] = exp(g-mx)/sum  (grid = ngraphs)
__global__ __launch_bounds__(256) void k_smstats(float* __restrict__ g) {
    __shared__ float red[256];
    int p = blockIdx.x, tid = threadIdx.x;
    float* gp = g + (long long)p * NN;
    float lmax = -INFINITY;
    for (int n = tid; n < NN; n += 256) lmax = fmaxf(lmax, gp[n]);
    red[tid] = lmax; __syncthreads();
    for (int s = 128; s > 0; s >>= 1) { if (tid < s) red[tid] = fmaxf(red[tid], red[tid + s]); __syncthreads(); }
    float mx = red[0]; __syncthreads();
    float lsum = 0.0f;
    for (int n = tid; n < NN; n += 256) { float e = expf(gp[n] - mx); gp[n] = e; lsum += e; }
    red[tid] = lsum; __syncthreads();
    for (int s = 128; s > 0; s >>= 1) { if (tid < s) red[tid] += red[tid + s]; __syncthreads(); }
    float inv = 1.0f / red[0];
    __syncthreads();
    for (int n = tid; n < NN; n += 256) gp[n] *= inv;
}

// weighted sum: out[rowbase+p][colOff+d] += sum_{rows} a[p*NN+n] * x[(p*NN+n)*128+d]
// grid = ngraphs * BPG blocks, 128 threads (one dim each)
__global__ __launch_bounds__(128) void k_wsum(
    const float* __restrict__ X, const float* __restrict__ a,
    float* __restrict__ ro, int rowbase, int colOff)
{
    int p = blockIdx.x / BPG;
    int chunk = blockIdx.x % BPG;
    int d = threadIdx.x;
    long long base = (long long)p * NN;
    int r0 = chunk * RB, r1 = r0 + RB;
    float s = 0.0f;
    for (int n = r0; n < r1; ++n) {
        float an = a[base + n];
        if (an != 0.0f) s += an * X[(base + n) * 128 + d];
    }
    atomicAdd(&ro[(long long)(rowbase + p) * 384 + colOff + d], s);
}

__global__ void k_colsum(const float* __restrict__ x, float* __restrict__ musum, int nrows) {
    int d = threadIdx.x;                  // 128 threads
    int r0 = blockIdx.x * 64;
    int r1 = min(r0 + 64, nrows);
    float s = 0.0f;
    for (int r = r0; r < r1; ++r) s += x[(long long)r * 128 + d];
    atomicAdd(&musum[d], s);
}

__global__ void k_colvar(const float* __restrict__ x, const float* __restrict__ musum,
                         const float* __restrict__ ms, float* __restrict__ varsum, int nrows) {
    int d = threadIdx.x;
    float c = (musum[d] / (float)nrows) * ms[d];
    int r0 = blockIdx.x * 64;
    int r1 = min(r0 + 64, nrows);
    float s = 0.0f;
    for (int r = r0; r < r1; ++r) { float o = x[(long long)r * 128 + d] - c; s += o * o; }
    atomicAdd(&varsum[d], s);
}

__global__ void k_gnorm_apply(const float* __restrict__ x, float* __restrict__ y,
                              const float* __restrict__ musum, const float* __restrict__ varsum,
                              const float* __restrict__ w, const float* __restrict__ b,
                              const float* __restrict__ ms, int nrows) {
    long long i = (long long)blockIdx.x * 256 + threadIdx.x;
    if (i >= (long long)nrows * 128) return;
    int d = (int)(i & 127);
    float mu = musum[d] / (float)nrows;
    float var = varsum[d] / (float)nrows;
    float o = x[i] - mu * ms[d];
    y[i] = w[d] * o * rsqrtf(var + 1e-5f) + b[d];
}

// t[i] = dot(X[i], wv)
__global__ __launch_bounds__(256) void k_dotvec(const float* __restrict__ X,
                                                const float* __restrict__ wv,
                                                float* __restrict__ t, int nrows) {
    __shared__ float wS[128];
    if (threadIdx.x < 128) wS[threadIdx.x] = wv[threadIdx.x];
    __syncthreads();
    int i = blockIdx.x * 256 + threadIdx.x;
    if (i >= nrows) return;
    const float4* xr = reinterpret_cast<const float4*>(X + (long long)i * 128);
    float s = 0.0f;
    #pragma unroll
    for (int k = 0; k < 32; ++k) {
        float4 v = xr[k];
        s += v.x * wS[4*k] + v.y * wS[4*k+1] + v.z * wS[4*k+2] + v.w * wS[4*k+3];
    }
    t[i] = s;
}

// sagg[sdst[e]-nbase] += t[ssrc[e]-nbase] * eal[e]
__global__ void k_scoreagg(const int* __restrict__ ssrc, const int* __restrict__ sdst,
                           const float* __restrict__ t, const float* __restrict__ eal,
                           float* __restrict__ sagg, int ne, int nbase) {
    int e = blockIdx.x * 256 + threadIdx.x;
    if (e >= ne) return;
    float w = eal[e];
    if (w != 0.0f) atomicAdd(&sagg[sdst[e] - nbase], t[ssrc[e] - nbase] * w);
}

// score[i] = sagg[i] + brel + dot(X[i], wroot)   (in place on sagg)
__global__ __launch_bounds__(256) void k_score(const float* __restrict__ X,
                                               const float* __restrict__ wroot,
                                               float* __restrict__ sagg,
                                               const float* __restrict__ brelp, int bi, int nrows) {
    __shared__ float wS[128];
    if (threadIdx.x < 128) wS[threadIdx.x] = wroot[threadIdx.x];
    __syncthreads();
    int i = blockIdx.x * 256 + threadIdx.x;
    if (i >= nrows) return;
    const float4* xr = reinterpret_cast<const float4*>(X + (long long)i * 128);
    float s = sagg[i] + brelp[bi];
    #pragma unroll
    for (int k = 0; k < 32; ++k) {
        float4 v = xr[k];
        s += v.x * wS[4*k] + v.y * wS[4*k+1] + v.z * wS[4*k+2] + v.w * wS[4*k+3];
    }
    sagg[i] = s;
}

// per-pathway top-k: select k largest (ties -> lowest index), update nalive in place
__global__ __launch_bounds__(256) void k_topk(const float* __restrict__ score,
                                              float* __restrict__ nalive, int k) {
    __shared__ unsigned keys[NN];
    __shared__ int red[256];
    __shared__ int chunkcnt[256];
    int p = blockIdx.x, tid = threadIdx.x;
    const float* sc = score + (long long)p * NN;
    float* na = nalive + (long long)p * NN;
    for (int n = tid; n < NN; n += 256)
        keys[n] = (na[n] > 0.5f) ? fkey(sc[n]) : 0u;
    __syncthreads();
    unsigned lo = 0u, hi = 0xFFFFFFFFu;
    while (lo < hi) {
        unsigned mid = (unsigned)(((unsigned long long)lo + (unsigned long long)hi + 1ull) >> 1);
        int c = 0;
        for (int n = tid; n < NN; n += 256) c += (keys[n] >= mid) ? 1 : 0;
        red[tid] = c; __syncthreads();
        for (int s = 128; s > 0; s >>= 1) { if (tid < s) red[tid] += red[tid + s]; __syncthreads(); }
        int total = red[0]; __syncthreads();
        if (total >= k) lo = mid; else hi = mid - 1;
    }
    unsigned V = lo;
    int cg = 0;
    for (int n = tid; n < NN; n += 256) cg += (keys[n] > V) ? 1 : 0;
    red[tid] = cg; __syncthreads();
    for (int s = 128; s > 0; s >>= 1) { if (tid < s) red[tid] += red[tid + s]; __syncthreads(); }
    int seleq = k - red[0]; __syncthreads();
    int c0 = tid * 32, c1 = min(c0 + 32, NN);
    int ceq = 0;
    for (int n = c0; n < c1; ++n) ceq += (keys[n] == V) ? 1 : 0;
    chunkcnt[tid] = ceq; __syncthreads();
    if (tid == 0) {
        int s = 0;
        for (int i = 0; i < 256; ++i) { int c = chunkcnt[i]; chunkcnt[i] = s; s += c; }
    }
    __syncthreads();
    int rank = chunkcnt[tid];
    for (int n = c0; n < c1; ++n) {
        unsigned kk = keys[n];
        bool sel = (kk > V) || (kk == V && rank < seleq);
        if (kk == V) rank++;
        na[n] = sel ? 1.0f : 0.0f;
    }
}

// X[i][d] = nalive[i] ? X[i][d] * tanh(score[i]) : 0
__global__ void k_maskapply(float* __restrict__ X, const float* __restrict__ score,
                            const float* __restrict__ nalive, long long total) {
    long long i = (long long)blockIdx.x * 256 + threadIdx.x;
    if (i >= total) return;
    long long row = i >> 7;
    float f = (nalive[row] > 0.5f) ? tanhf(score[row]) : 0.0f;
    X[i] *= f;
}

__global__ void k_ealive(const int* __restrict__ ssrc, const int* __restrict__ sdst,
                         const float* __restrict__ nalive, float* __restrict__ eal,
                         int ne, int nbase) {
    int e = blockIdx.x * 256 + threadIdx.x;
    if (e >= ne) return;
    if (nalive[ssrc[e] - nbase] < 0.5f || nalive[sdst[e] - nbase] < 0.5f) eal[e] = 0.0f;
}

__global__ __launch_bounds__(64) void k_head(
    const float* __restrict__ ro, const float* __restrict__ lin_w, const float* __restrict__ lin_b,
    const float* __restrict__ m1w, const float* __restrict__ m1b,
    const float* __restrict__ m2w, const float* __restrict__ m2b,
    const float* __restrict__ m3w, const float* __restrict__ m3b, float* __restrict__ out)
{
    __shared__ float v[33], h1[48], h2[16];
    int t = threadIdx.x;
    if (t < 33) {
        float s = lin_b[0];
        for (int k = 0; k < 384; ++k) s += ro[t * 384 + k] * lin_w[k];
        v[t] = tanhf(s);
    }
    __syncthreads();
    if (t < 48) {
        float s = m1b[t];
        for (int i = 0; i < 33; ++i) s += v[i] * m1w[i * 48 + t];
        h1[t] = tanhf(s);
    }
    __syncthreads();
    if (t < 16) {
        float s = m2b[t];
        for (int i = 0; i < 48; ++i) s += h1[i] * m2w[i * 16 + t];
        h2[t] = tanhf(s);
    }
    __syncthreads();
    if (t == 0) {
        float s = m3b[0];
        for (int i = 0; i < 16; ++i) s += h2[i] * m3w[i];
        float s1 = 1.0f / (1.0f + expf(-s));
        out[0] = 1.0f / (1.0f + expf(-s1));
    }
}

static inline int cdiv(long long a, long long b) { return (int)((a + b - 1) / b); }

extern "C" void kernel_launch(void* const* d_in, const int* in_sizes, int n_in,
                              void* d_out, int out_size, void* d_ws, size_t ws_size,
                              hipStream_t stream)
{
    (void)in_sizes; (void)n_in; (void)out_size; (void)ws_size;
    const float* h     = (const float*)d_in[0];
    const int*   eidx  = (const int*)d_in[1];
    const int*   seidx = (const int*)d_in[2];
    const float* Wl_a  = (const float*)d_in[3];
    const float* Wr_a  = (const float*)d_in[4];
    const float* bl_a  = (const float*)d_in[5];
    const float* Wl_s  = (const float*)d_in[6];
    const float* Wr_s  = (const float*)d_in[7];
    const float* bl_s  = (const float*)d_in[8];
    const float* gate_w = (const float*)d_in[9];
    const float* gate_b = (const float*)d_in[10];
    const float* p_wrel = (const float*)d_in[11];
    const float* p_brel = (const float*)d_in[12];
    const float* p_wroot= (const float*)d_in[13];
    const float* nw    = (const float*)d_in[14];
    const float* nb    = (const float*)d_in[15];
    const float* nms   = (const float*)d_in[16];
    const float* lin_w = (const float*)d_in[17];
    const float* lin_b = (const float*)d_in[18];
    const float* m1w   = (const float*)d_in[19];
    const float* m1b   = (const float*)d_in[20];
    const float* m2w   = (const float*)d_in[21];
    const float* m2b   = (const float*)d_in[22];
    const float* m3w   = (const float*)d_in[23];
    const float* m3b   = (const float*)d_in[24];
    float* out = (float*)d_out;

    const int* esrc = eidx;
    const int* edst = eidx + EG;

    float* W = (float*)d_ws;
    size_t off = 0;
    auto alloc = [&](size_t nf) { float* p = W + off; off += (nf + 63) & ~(size_t)63; return p; };
    float* Xc    = alloc((size_t)CH_N * DD);
    float* AGGc  = alloc((size_t)CH_N * DD);
    float* xa    = alloc((size_t)NN * DD);
    float* xb    = alloc((size_t)NN * DD);
    float* agg1  = alloc((size_t)NN * DD);
    float* deg1  = alloc(NN);
    float* deg2  = alloc(CH_N);
    float* tbuf  = alloc(CH_N);
    float* sagg  = alloc(CH_N);
    float* nal   = alloc(CH_N);
    float* eal   = alloc(CH_E);
    float* gbuf  = alloc(CH_N);
    float* ro    = alloc(33 * 384);
    float* musum = alloc(128);
    float* varsum= alloc(128);

    hipMemsetAsync(ro, 0, 33 * 384 * sizeof(float), stream);

    // ================= stage 1 =================
    k_fill<<<cdiv(NN,256),256,0,stream>>>(deg1, 1.0f, NN);
    k_deg<<<cdiv(EG,256),256,0,stream>>>(edst, (const float*)nullptr, deg1, EG, 0);

    // layer a (DIN=16)
    hipMemcpyAsync(agg1, h, (size_t)NN * DI * sizeof(float), hipMemcpyDeviceToDevice, stream);
    k_agg<<<cdiv((long long)EG*DI,256),256,0,stream>>>(esrc, edst, h, (const float*)nullptr, agg1, EG, 4, 0, 0);
    k_sage16<<<cdiv((long long)NN*DD,256),256,0,stream>>>(h, agg1, deg1, Wl_a, Wr_a, bl_a, xa, NN);
    k_gate<<<cdiv(NN,256),256,0,stream>>>(xa, (const float*)nullptr, gate_w + 0*DD, gate_b, 0, gbuf, NN);
    k_smstats<<<1,256,0,stream>>>(gbuf);
    k_wsum<<<BPG,128,0,stream>>>(xa, gbuf, ro, 0, 0);

    // gnorm 1: xa -> xb
    hipMemsetAsync(musum, 0, 128*sizeof(float), stream);
    hipMemsetAsync(varsum, 0, 128*sizeof(float), stream);
    k_colsum<<<cdiv(NN,64),128,0,stream>>>(xa, musum, NN);
    k_colvar<<<cdiv(NN,64),128,0,stream>>>(xa, musum, nms, varsum, NN);
    k_gnorm_apply<<<cdiv((long long)NN*DD,256),256,0,stream>>>(xa, xb, musum, varsum, nw, nb, nms, NN);

    // layer b
    hipMemcpyAsync(agg1, xb, (size_t)NN * DD * sizeof(float), hipMemcpyDeviceToDevice, stream);
    k_agg<<<cdiv((long long)EG*DD,256),256,0,stream>>>(esrc, edst, xb, (const float*)nullptr, agg1, EG, 7, 0, 0);
    k_sage128<<<cdiv(NN,32),256,0,stream>>>(xb, agg1, deg1, Wl_s + 0*16384, Wr_s + 0*16384, bl_s + 0*128, xa, NN, 0);
    k_gate<<<cdiv(NN,256),256,0,stream>>>(xa, (const float*)nullptr, gate_w + 1*DD, gate_b, 1, gbuf, NN);
    k_smstats<<<1,256,0,stream>>>(gbuf);
    k_wsum<<<BPG,128,0,stream>>>(xa, gbuf, ro, 0, 128);

    // gnorm 2: xa -> xb
    hipMemsetAsync(musum, 0, 128*sizeof(float), stream);
    hipMemsetAsync(varsum, 0, 128*sizeof(float), stream);
    k_colsum<<<cdiv(NN,64),128,0,stream>>>(xa, musum, NN);
    k_colvar<<<cdiv(NN,64),128,0,stream>>>(xa, musum, nms, varsum, NN);
    k_gnorm_apply<<<cdiv((long long)NN*DD,256),256,0,stream>>>(xa, xb, musum, varsum, nw, nb, nms, NN);

    // layer c -> xa = x_c
    hipMemcpyAsync(agg1, xb, (size_t)NN * DD * sizeof(float), hipMemcpyDeviceToDevice, stream);
    k_agg<<<cdiv((long long)EG*DD,256),256,0,stream>>>(esrc, edst, xb, (const float*)nullptr, agg1, EG, 7, 0, 0);
    k_sage128<<<cdiv(NN,32),256,0,stream>>>(xb, agg1, deg1, Wl_s + 1*16384, Wr_s + 1*16384, bl_s + 1*128, xa, NN, 0);
    k_gate<<<cdiv(NN,256),256,0,stream>>>(xa, (const float*)nullptr, gate_w + 2*DD, gate_b, 2, gbuf, NN);
    k_smstats<<<1,256,0,stream>>>(gbuf);
    k_wsum<<<BPG,128,0,stream>>>(xa, gbuf, ro, 0, 256);

    // ================= stage 2 (chunked over pathways) =================
    for (int c = 0; c < NCH; ++c) {
        const int* ssrc = seidx + (size_t)c * CH_E;
        const int* sdst = seidx + ES_TOT + (size_t)c * CH_E;
        int nbase = c * CH_N;

        k_fill<<<cdiv(CH_N,256),256,0,stream>>>(nal, 1.0f, CH_N);
        k_fill<<<cdiv(CH_E,256),256,0,stream>>>(eal, 1.0f, CH_E);

        for (int layer = 0; layer < 3; ++layer) {
            const float* Wl = Wl_s + (2 + layer) * 16384;
            const float* Wr = Wr_s + (2 + layer) * 16384;
            const float* bl = bl_s + (2 + layer) * 128;
            int kkeep = (layer == 0) ? KK1 : (layer == 1) ? KK2 : KK3;
            int gi = 3 + layer;

            hipMemsetAsync(AGGc, 0, (size_t)CH_N * DD * sizeof(float), stream);
            hipMemsetAsync(deg2, 0, (size_t)CH_N * sizeof(float), stream);
            k_deg<<<cdiv(CH_E,256),256,0,stream>>>(sdst, eal, deg2, CH_E, nbase);
            if (layer == 0) {
                k_agg<<<cdiv((long long)CH_E*DD,256),256,0,stream>>>(ssrc, sdst, xa, eal, AGGc, CH_E, 7, 1, nbase);
                k_sage128<<<cdiv(CH_N,32),256,0,stream>>>(xa, AGGc, deg2, Wl, Wr, bl, Xc, CH_N, 1);
            } else {
                k_agg<<<cdiv((long long)CH_E*DD,256),256,0,stream>>>(ssrc, sdst, Xc, eal, AGGc, CH_E, 7, 0, nbase);
                k_sage128<<<cdiv(CH_N,32),256,0,stream>>>(Xc, AGGc, deg2, Wl, Wr, bl, Xc, CH_N, 0);
            }

            // SAGPool
            k_dotvec<<<cdiv(CH_N,256),256,0,stream>>>(Xc, p_wrel + layer*DD, tbuf, CH_N);
            hipMemsetAsync(sagg, 0, (size_t)CH_N * sizeof(float), stream);
            k_scoreagg<<<cdiv(CH_E,256),256,0,stream>>>(ssrc, sdst, tbuf, eal, sagg, CH_E, nbase);
            k_score<<<cdiv(CH_N,256),256,0,stream>>>(Xc, p_wroot + layer*DD, sagg, p_brel, layer, CH_N);
            k_topk<<<CH_P,256,0,stream>>>(sagg, nal, kkeep);
            k_maskapply<<<cdiv((long long)CH_N*DD,256),256,0,stream>>>(Xc, sagg, nal, (long long)CH_N * DD);
            k_ealive<<<cdiv(CH_E,256),256,0,stream>>>(ssrc, sdst, nal, eal, CH_E, nbase);

            // readout -> ro rows 1 + c*CH_P + p, column block = layer*128
            k_gate<<<cdiv(CH_N,256),256,0,stream>>>(Xc, nal, gate_w + gi*DD, gate_b, gi, gbuf, CH_N);
            k_smstats<<<CH_P,256,0,stream>>>(gbuf);
            k_wsum<<<CH_P*BPG,128,0,stream>>>(Xc, gbuf, ro, 1 + c*CH_P, layer*128);
        }
    }

    // ================= head =================
    k_head<<<1,64,0,stream>>>(ro, lin_w, lin_b, m1w, m1b, m2w, m2b, m3w, m3b, out);
}

// Round 4
// 2622.769 us; speedup vs baseline: 5.6883x; 1.4921x over previous
//
#include <hip/hip_runtime.h>
#include <math.h>

#define NN      8000
#define PP      32
#define EG      128000
#define ES_TOT  131072     // P * 4096
#define ES_P    4096
#define DI      16
#define DD      128
#define KK1     6400
#define KK2     5120
#define KK3     4096
#define CH_P    8                    // pathways per chunk
#define NCH     (PP / CH_P)          // 4 chunks
#define CH_N    (CH_P * NN)          // 64000 nodes per chunk
#define CH_E    (CH_P * ES_P)        // 32768 edges per chunk
#define RB      64                   // rows per k_wsum block
#define BPG     (NN / RB)            // 125 blocks per graph

static __device__ __forceinline__ unsigned fkey(float f) {
    unsigned u = __float_as_uint(f);
    return (u & 0x80000000u) ? ~u : (u | 0x80000000u);
}

__global__ void k_fill(float* p, float v, int n) {
    int i = blockIdx.x * 256 + threadIdx.x;
    if (i < n) p[i] = v;
}

__global__ void k_deg(const int* __restrict__ dst, const float* __restrict__ w,
                      float* __restrict__ deg, int ne, int nbase) {
    int e = blockIdx.x * 256 + threadIdx.x;
    if (e >= ne) return;
    float we = w ? w[e] : 1.0f;
    if (we != 0.0f) atomicAdd(&deg[dst[e] - nbase], we);
}

// agg[(dst[e]-nbase)*Dd + d] += x[srow*Dd + d] * w[e];  Dd=1<<shift
__global__ void k_agg(const int* __restrict__ src, const int* __restrict__ dst,
                      const float* __restrict__ x, const float* __restrict__ w,
                      float* __restrict__ agg, int ne, int shift, int xModN, int nbase) {
    long long idx = (long long)blockIdx.x * 256 + threadIdx.x;
    int e = (int)(idx >> shift);
    if (e >= ne) return;
    int Dd = 1 << shift;
    int d = (int)idx & (Dd - 1);
    float we = w ? w[e] : 1.0f;
    if (we == 0.0f) return;
    int s = src[e];
    s = xModN ? (s % NN) : (s - nbase);
    atomicAdd(&agg[(long long)(dst[e] - nbase) * Dd + d], x[(long long)s * Dd + d] * we);
}

// y = tanh( (agg/deg) @ Wl + bl + h @ Wr ), K=16
__global__ __launch_bounds__(256) void k_sage16(
    const float* __restrict__ h, const float* __restrict__ agg, const float* __restrict__ deg,
    const float* __restrict__ Wl, const float* __restrict__ Wr, const float* __restrict__ bl,
    float* __restrict__ y, int nrows)
{
    __shared__ float WlS[16][128], WrS[16][128];
    int tid = threadIdx.x;
    for (int i = tid; i < 16 * 128; i += 256) {
        WlS[i >> 7][i & 127] = Wl[i];
        WrS[i >> 7][i & 127] = Wr[i];
    }
    __syncthreads();
    long long o = (long long)blockIdx.x * 256 + tid;
    int row = (int)(o >> 7);
    if (row >= nrows) return;
    int d = (int)o & 127;
    float invd = 1.0f / fmaxf(deg[row], 1.0f);
    float s = bl[d];
    #pragma unroll
    for (int k = 0; k < 16; ++k)
        s += agg[row * 16 + k] * invd * WlS[k][d] + h[row * 16 + k] * WrS[k][d];
    y[(long long)row * 128 + d] = tanhf(s);
}

// y = tanh( (agg/deg)@Wl + bl + x@Wr ), K=256 combined. BM=64,BN=128,BK=32, 8x4/thread.
// If tbuf!=null also emits t=y@wrel, rootd=y@wroot per row (SAGPool score parts).
// Grids must divide: nrows % 64 == 0 (8000, 64000 both do).
__global__ __launch_bounds__(256) void k_sage_v2(
    const float* __restrict__ x, const float* __restrict__ agg, const float* __restrict__ deg,
    const float* __restrict__ Wl, const float* __restrict__ Wr, const float* __restrict__ bl,
    float* __restrict__ y, int xModN,
    const float* __restrict__ wrel, const float* __restrict__ wroot,
    float* __restrict__ tbuf, float* __restrict__ rootd)
{
    __shared__ float Ws[32 * 128];
    __shared__ float Is[32][68];     // stride 68: write banks (4k+row)%32 -> 2-way, reads 16B-aligned
    __shared__ float wrelS[128], wrootS[128];
    int tid = threadIdx.x;
    long long row0 = (long long)blockIdx.x * 64;
    if (tbuf) {
        if (tid < 128) wrelS[tid] = wrel[tid];
        else if (tid < 256) wrootS[tid - 128] = wroot[tid - 128];
    }
    int tx = tid & 31, ty = tid >> 5;
    int srow = tid & 63;
    int koff = (tid >> 6) * 8;
    const float* aggrow = agg + (row0 + srow) * 128;
    long long xr = xModN ? ((row0 + srow) % NN) : (row0 + srow);
    const float* xrow = x + xr * 128;
    float invds = 1.0f / fmaxf(deg[row0 + srow], 1.0f);
    float acc[8][4] = {};
    for (int kb = 0; kb < 8; ++kb) {
        __syncthreads();
        const float* Wsrc = (kb < 4) ? (Wl + kb * 32 * 128) : (Wr + (kb - 4) * 32 * 128);
        #pragma unroll
        for (int j = 0; j < 4; ++j) {
            int fl = j * 1024 + tid * 4;
            *reinterpret_cast<float4*>(&Ws[fl]) = *reinterpret_cast<const float4*>(&Wsrc[fl]);
        }
        {
            const float* src = (kb < 4) ? (aggrow + kb * 32 + koff) : (xrow + (kb - 4) * 32 + koff);
            float4 v0 = *reinterpret_cast<const float4*>(src);
            float4 v1 = *reinterpret_cast<const float4*>(src + 4);
            float m = (kb < 4) ? invds : 1.0f;
            Is[koff + 0][srow] = v0.x * m; Is[koff + 1][srow] = v0.y * m;
            Is[koff + 2][srow] = v0.z * m; Is[koff + 3][srow] = v0.w * m;
            Is[koff + 4][srow] = v1.x * m; Is[koff + 5][srow] = v1.y * m;
            Is[koff + 6][srow] = v1.z * m; Is[koff + 7][srow] = v1.w * m;
        }
        __syncthreads();
        #pragma unroll
        for (int kk = 0; kk < 32; ++kk) {
            float4 wv = *reinterpret_cast<const float4*>(&Ws[kk * 128 + tx * 4]);
            float4 a0 = *reinterpret_cast<const float4*>(&Is[kk][ty * 8]);
            float4 a1 = *reinterpret_cast<const float4*>(&Is[kk][ty * 8 + 4]);
            float ia[8] = {a0.x, a0.y, a0.z, a0.w, a1.x, a1.y, a1.z, a1.w};
            float wa[4] = {wv.x, wv.y, wv.z, wv.w};
            #pragma unroll
            for (int i = 0; i < 8; ++i)
                #pragma unroll
                for (int j = 0; j < 4; ++j)
                    acc[i][j] += ia[i] * wa[j];
        }
    }
    float4 blv = *reinterpret_cast<const float4*>(&bl[tx * 4]);
    float blr[4] = {blv.x, blv.y, blv.z, blv.w};
    #pragma unroll
    for (int i = 0; i < 8; ++i) {
        long long row = row0 + ty * 8 + i;
        float yv[4];
        #pragma unroll
        for (int j = 0; j < 4; ++j) yv[j] = tanhf(acc[i][j] + blr[j]);
        *reinterpret_cast<float4*>(&y[row * 128 + tx * 4]) = make_float4(yv[0], yv[1], yv[2], yv[3]);
        if (tbuf) {
            float tp = yv[0] * wrelS[tx*4] + yv[1] * wrelS[tx*4+1] + yv[2] * wrelS[tx*4+2] + yv[3] * wrelS[tx*4+3];
            float rp = yv[0] * wrootS[tx*4] + yv[1] * wrootS[tx*4+1] + yv[2] * wrootS[tx*4+2] + yv[3] * wrootS[tx*4+3];
            #pragma unroll
            for (int m = 16; m >= 1; m >>= 1) {
                tp += __shfl_xor(tp, m, 32);
                rp += __shfl_xor(rp, m, 32);
            }
            if (tx == 0) { tbuf[row] = tp; rootd[row] = rp; }
        }
    }
}

// stage-1 gate (no mask): g[i] = dot(x[i],gw)+gb
__global__ __launch_bounds__(256) void k_gate(
    const float* __restrict__ X, const float* __restrict__ gw,
    const float* __restrict__ gbp, int gi, float* __restrict__ g, int nrows)
{
    __shared__ float wS[128];
    if (threadIdx.x < 128) wS[threadIdx.x] = gw[threadIdx.x];
    __syncthreads();
    int i = blockIdx.x * 256 + threadIdx.x;
    if (i >= nrows) return;
    const float4* xrp = reinterpret_cast<const float4*>(X + (long long)i * 128);
    float s = gbp[gi];
    #pragma unroll
    for (int k = 0; k < 32; ++k) {
        float4 v = xrp[k];
        s += v.x * wS[4*k] + v.y * wS[4*k+1] + v.z * wS[4*k+2] + v.w * wS[4*k+3];
    }
    g[i] = s;
}

// fused: X[row] *= (alive ? tanh(score) : 0), g[row] = alive ? dot(Xnew,gw)+gb : -inf
// one wave per row, 4 rows per block
__global__ __launch_bounds__(256) void k_maskgate(
    float* __restrict__ X, const float* __restrict__ score, const float* __restrict__ nalive,
    const float* __restrict__ gw, const float* __restrict__ gbp, int gi,
    float* __restrict__ g)
{
    __shared__ float gwS[128];
    int tid = threadIdx.x;
    if (tid < 128) gwS[tid] = gw[tid];
    __syncthreads();
    int wv = tid >> 6, lane = tid & 63;
    long long row = (long long)blockIdx.x * 4 + wv;
    bool alive = nalive[row] > 0.5f;
    float f = alive ? tanhf(score[row]) : 0.0f;
    float2 v = *reinterpret_cast<float2*>(&X[row * 128 + lane * 2]);
    v.x *= f; v.y *= f;
    *reinterpret_cast<float2*>(&X[row * 128 + lane * 2]) = v;
    float gp = v.x * gwS[lane * 2] + v.y * gwS[lane * 2 + 1];
    #pragma unroll
    for (int m = 32; m >= 1; m >>= 1) gp += __shfl_xor(gp, m, 64);
    if (lane == 0) g[row] = alive ? (gp + gbp[gi]) : -INFINITY;
}

// per-graph softmax stats: g -> exp(g-max) in place, invp[p] = 1/sum
__global__ __launch_bounds__(1024) void k_smstats(float* __restrict__ g, float* __restrict__ invp) {
    __shared__ float red[1024];
    int p = blockIdx.x, tid = threadIdx.x;
    float* gp = g + (long long)p * NN;
    float lmax = -INFINITY;
    for (int n = tid; n < NN; n += 1024) lmax = fmaxf(lmax, gp[n]);
    red[tid] = lmax; __syncthreads();
    for (int s = 512; s > 0; s >>= 1) { if (tid < s) red[tid] = fmaxf(red[tid], red[tid + s]); __syncthreads(); }
    float mx = red[0]; __syncthreads();
    float ls = 0.0f;
    for (int n = tid; n < NN; n += 1024) { float e = expf(gp[n] - mx); gp[n] = e; ls += e; }
    red[tid] = ls; __syncthreads();
    for (int s = 512; s > 0; s >>= 1) { if (tid < s) red[tid] += red[tid + s]; __syncthreads(); }
    if (tid == 0) invp[p] = 1.0f / red[0];
}

// out[rowbase+p][colOff+d] += invp[p] * sum_{rows chunk} a[p*NN+n]*x[...]
__global__ __launch_bounds__(128) void k_wsum(
    const float* __restrict__ X, const float* __restrict__ a, const float* __restrict__ invp,
    float* __restrict__ ro, int rowbase, int colOff)
{
    int p = blockIdx.x / BPG;
    int chunk = blockIdx.x % BPG;
    int d = threadIdx.x;
    long long base = (long long)p * NN;
    int r0 = chunk * RB, r1 = r0 + RB;
    float s = 0.0f;
    for (int n = r0; n < r1; ++n) {
        float an = a[base + n];
        if (an != 0.0f) s += an * X[(base + n) * 128 + d];
    }
    atomicAdd(&ro[(long long)(rowbase + p) * 384 + colOff + d], s * invp[p]);
}

__global__ void k_colsum(const float* __restrict__ x, float* __restrict__ musum, int nrows) {
    int d = threadIdx.x;
    int r0 = blockIdx.x * 64;
    int r1 = min(r0 + 64, nrows);
    float s = 0.0f;
    for (int r = r0; r < r1; ++r) s += x[(long long)r * 128 + d];
    atomicAdd(&musum[d], s);
}

__global__ void k_colvar(const float* __restrict__ x, const float* __restrict__ musum,
                         const float* __restrict__ ms, float* __restrict__ varsum, int nrows) {
    int d = threadIdx.x;
    float c = (musum[d] / (float)nrows) * ms[d];
    int r0 = blockIdx.x * 64;
    int r1 = min(r0 + 64, nrows);
    float s = 0.0f;
    for (int r = r0; r < r1; ++r) { float o = x[(long long)r * 128 + d] - c; s += o * o; }
    atomicAdd(&varsum[d], s);
}

__global__ void k_gnorm_apply(const float* __restrict__ x, float* __restrict__ y,
                              const float* __restrict__ musum, const float* __restrict__ varsum,
                              const float* __restrict__ w, const float* __restrict__ b,
                              const float* __restrict__ ms, int nrows) {
    long long i = (long long)blockIdx.x * 256 + threadIdx.x;
    if (i >= (long long)nrows * 128) return;
    int d = (int)(i & 127);
    float mu = musum[d] / (float)nrows;
    float var = varsum[d] / (float)nrows;
    float o = x[i] - mu * ms[d];
    y[i] = w[d] * o * rsqrtf(var + 1e-5f) + b[d];
}

__global__ void k_scoreagg(const int* __restrict__ ssrc, const int* __restrict__ sdst,
                           const float* __restrict__ t, const float* __restrict__ eal,
                           float* __restrict__ sagg, int ne, int nbase) {
    int e = blockIdx.x * 256 + threadIdx.x;
    if (e >= ne) return;
    float w = eal[e];
    if (w != 0.0f) atomicAdd(&sagg[sdst[e] - nbase], t[ssrc[e] - nbase] * w);
}

// radix-select top-k per pathway. sagg in: edge-agg part; out: full score.
// Also needs rootd (x@wroot). keys=0 for dead rows (real keys always > 0).
__global__ __launch_bounds__(256) void k_topk(
    float* __restrict__ sagg, const float* __restrict__ rootd,
    const float* __restrict__ brelp, int bi,
    float* __restrict__ nalive, int k)
{
    __shared__ unsigned keys[NN];
    __shared__ int hist[256];
    __shared__ int chunkcnt[256];
    __shared__ unsigned sh_pref;
    __shared__ int sh_kneed;
    int p = blockIdx.x, tid = threadIdx.x;
    float* sc = sagg + (long long)p * NN;
    const float* rd = rootd + (long long)p * NN;
    float* na = nalive + (long long)p * NN;
    float brel = brelp[bi];
    for (int n = tid; n < NN; n += 256) {
        float s = sc[n] + brel + rd[n];
        sc[n] = s;
        keys[n] = (na[n] > 0.5f) ? fkey(s) : 0u;
    }
    if (tid == 0) { sh_pref = 0u; sh_kneed = k; }
    __syncthreads();
    for (int lvl = 3; lvl >= 0; --lvl) {
        int sh = lvl * 8;
        hist[tid] = 0;
        unsigned pref = sh_pref; int kneed = sh_kneed;
        unsigned pmask = (lvl == 3) ? 0u : (0xFFFFFFFFu << (8 * (lvl + 1)));
        __syncthreads();
        for (int n = tid; n < NN; n += 256) {
            unsigned kv = keys[n];
            if ((kv & pmask) == pref) atomicAdd(&hist[(kv >> sh) & 255], 1);
        }
        __syncthreads();
        if (tid == 0) {
            int cum = 0, b = 255;
            for (; b >= 0; --b) { cum += hist[b]; if (cum >= kneed) break; }
            sh_pref = pref | ((unsigned)b << sh);
            sh_kneed = kneed - (cum - hist[b]);
        }
        __syncthreads();
    }
    unsigned V = sh_pref;
    int seleq = sh_kneed;
    int c0 = tid * 32, c1 = min(c0 + 32, NN);
    int ceq = 0;
    for (int n = c0; n < c1; ++n) ceq += (keys[n] == V) ? 1 : 0;
    chunkcnt[tid] = ceq; __syncthreads();
    if (tid == 0) {
        int s = 0;
        for (int i = 0; i < 256; ++i) { int c = chunkcnt[i]; chunkcnt[i] = s; s += c; }
    }
    __syncthreads();
    int rank = chunkcnt[tid];
    for (int n = c0; n < c1; ++n) {
        unsigned kk = keys[n];
        bool sel = (kk > V) || (kk == V && rank < seleq);
        if (kk == V) rank++;
        na[n] = sel ? 1.0f : 0.0f;
    }
}

__global__ void k_ealive(const int* __restrict__ ssrc, const int* __restrict__ sdst,
                         const float* __restrict__ nalive, float* __restrict__ eal,
                         int ne, int nbase) {
    int e = blockIdx.x * 256 + threadIdx.x;
    if (e >= ne) return;
    if (nalive[ssrc[e] - nbase] < 0.5f || nalive[sdst[e] - nbase] < 0.5f) eal[e] = 0.0f;
}

__global__ __launch_bounds__(64) void k_head(
    const float* __restrict__ ro, const float* __restrict__ lin_w, const float* __restrict__ lin_b,
    const float* __restrict__ m1w, const float* __restrict__ m1b,
    const float* __restrict__ m2w, const float* __restrict__ m2b,
    const float* __restrict__ m3w, const float* __restrict__ m3b, float* __restrict__ out)
{
    __shared__ float v[33], h1[48], h2[16];
    int t = threadIdx.x;
    if (t < 33) {
        float s = lin_b[0];
        for (int k = 0; k < 384; ++k) s += ro[t * 384 + k] * lin_w[k];
        v[t] = tanhf(s);
    }
    __syncthreads();
    if (t < 48) {
        float s = m1b[t];
        for (int i = 0; i < 33; ++i) s += v[i] * m1w[i * 48 + t];
        h1[t] = tanhf(s);
    }
    __syncthreads();
    if (t < 16) {
        float s = m2b[t];
        for (int i = 0; i < 48; ++i) s += h1[i] * m2w[i * 16 + t];
        h2[t] = tanhf(s);
    }
    __syncthreads();
    if (t == 0) {
        float s = m3b[0];
        for (int i = 0; i < 16; ++i) s += h2[i] * m3w[i];
        float s1 = 1.0f / (1.0f + expf(-s));
        out[0] = 1.0f / (1.0f + expf(-s1));
    }
}

static inline int cdiv(long long a, long long b) { return (int)((a + b - 1) / b); }

extern "C" void kernel_launch(void* const* d_in, const int* in_sizes, int n_in,
                              void* d_out, int out_size, void* d_ws, size_t ws_size,
                              hipStream_t stream)
{
    (void)in_sizes; (void)n_in; (void)out_size; (void)ws_size;
    const float* h     = (const float*)d_in[0];
    const int*   eidx  = (const int*)d_in[1];
    const int*   seidx = (const int*)d_in[2];
    const float* Wl_a  = (const float*)d_in[3];
    const float* Wr_a  = (const float*)d_in[4];
    const float* bl_a  = (const float*)d_in[5];
    const float* Wl_s  = (const float*)d_in[6];
    const float* Wr_s  = (const float*)d_in[7];
    const float* bl_s  = (const float*)d_in[8];
    const float* gate_w = (const float*)d_in[9];
    const float* gate_b = (const float*)d_in[10];
    const float* p_wrel = (const float*)d_in[11];
    const float* p_brel = (const float*)d_in[12];
    const float* p_wroot= (const float*)d_in[13];
    const float* nw    = (const float*)d_in[14];
    const float* nb    = (const float*)d_in[15];
    const float* nms   = (const float*)d_in[16];
    const float* lin_w = (const float*)d_in[17];
    const float* lin_b = (const float*)d_in[18];
    const float* m1w   = (const float*)d_in[19];
    const float* m1b   = (const float*)d_in[20];
    const float* m2w   = (const float*)d_in[21];
    const float* m2b   = (const float*)d_in[22];
    const float* m3w   = (const float*)d_in[23];
    const float* m3b   = (const float*)d_in[24];
    float* out = (float*)d_out;

    const int* esrc = eidx;
    const int* edst = eidx + EG;

    float* W = (float*)d_ws;
    size_t off = 0;
    auto alloc = [&](size_t nf) { float* p = W + off; off += (nf + 63) & ~(size_t)63; return p; };
    float* Xc    = alloc((size_t)CH_N * DD);
    float* AGGc  = alloc((size_t)CH_N * DD);
    float* xa    = alloc((size_t)NN * DD);
    float* xb    = alloc((size_t)NN * DD);
    float* agg1  = alloc((size_t)NN * DD);
    float* deg1  = alloc(NN);
    float* deg2  = alloc(CH_N);
    float* tbuf  = alloc(CH_N);
    float* rootd = alloc(CH_N);
    float* sagg  = alloc(CH_N);
    float* nal   = alloc(CH_N);
    float* eal   = alloc(CH_E);
    float* gbuf  = alloc(CH_N);
    float* invp  = alloc(64);
    float* ro    = alloc(33 * 384);
    float* musum = alloc(128);
    float* varsum= alloc(128);

    hipMemsetAsync(ro, 0, 33 * 384 * sizeof(float), stream);

    // ================= stage 1 =================
    k_fill<<<cdiv(NN,256),256,0,stream>>>(deg1, 1.0f, NN);
    k_deg<<<cdiv(EG,256),256,0,stream>>>(edst, (const float*)nullptr, deg1, EG, 0);

    // layer a (DIN=16)
    hipMemcpyAsync(agg1, h, (size_t)NN * DI * sizeof(float), hipMemcpyDeviceToDevice, stream);
    k_agg<<<cdiv((long long)EG*DI,256),256,0,stream>>>(esrc, edst, h, (const float*)nullptr, agg1, EG, 4, 0, 0);
    k_sage16<<<cdiv((long long)NN*DD,256),256,0,stream>>>(h, agg1, deg1, Wl_a, Wr_a, bl_a, xa, NN);
    k_gate<<<cdiv(NN,256),256,0,stream>>>(xa, gate_w + 0*DD, gate_b, 0, gbuf, NN);
    k_smstats<<<1,1024,0,stream>>>(gbuf, invp);
    k_wsum<<<BPG,128,0,stream>>>(xa, gbuf, invp, ro, 0, 0);

    // gnorm 1: xa -> xb
    hipMemsetAsync(musum, 0, 128*sizeof(float), stream);
    hipMemsetAsync(varsum, 0, 128*sizeof(float), stream);
    k_colsum<<<cdiv(NN,64),128,0,stream>>>(xa, musum, NN);
    k_colvar<<<cdiv(NN,64),128,0,stream>>>(xa, musum, nms, varsum, NN);
    k_gnorm_apply<<<cdiv((long long)NN*DD,256),256,0,stream>>>(xa, xb, musum, varsum, nw, nb, nms, NN);

    // layer b
    hipMemcpyAsync(agg1, xb, (size_t)NN * DD * sizeof(float), hipMemcpyDeviceToDevice, stream);
    k_agg<<<cdiv((long long)EG*DD,256),256,0,stream>>>(esrc, edst, xb, (const float*)nullptr, agg1, EG, 7, 0, 0);
    k_sage_v2<<<NN/64,256,0,stream>>>(xb, agg1, deg1, Wl_s + 0*16384, Wr_s + 0*16384, bl_s + 0*128, xa, 0,
                                      nullptr, nullptr, nullptr, nullptr);
    k_gate<<<cdiv(NN,256),256,0,stream>>>(xa, gate_w + 1*DD, gate_b, 1, gbuf, NN);
    k_smstats<<<1,1024,0,stream>>>(gbuf, invp);
    k_wsum<<<BPG,128,0,stream>>>(xa, gbuf, invp, ro, 0, 128);

    // gnorm 2: xa -> xb
    hipMemsetAsync(musum, 0, 128*sizeof(float), stream);
    hipMemsetAsync(varsum, 0, 128*sizeof(float), stream);
    k_colsum<<<cdiv(NN,64),128,0,stream>>>(xa, musum, NN);
    k_colvar<<<cdiv(NN,64),128,0,stream>>>(xa, musum, nms, varsum, NN);
    k_gnorm_apply<<<cdiv((long long)NN*DD,256),256,0,stream>>>(xa, xb, musum, varsum, nw, nb, nms, NN);

    // layer c -> xa = x_c
    hipMemcpyAsync(agg1, xb, (size_t)NN * DD * sizeof(float), hipMemcpyDeviceToDevice, stream);
    k_agg<<<cdiv((long long)EG*DD,256),256,0,stream>>>(esrc, edst, xb, (const float*)nullptr, agg1, EG, 7, 0, 0);
    k_sage_v2<<<NN/64,256,0,stream>>>(xb, agg1, deg1, Wl_s + 1*16384, Wr_s + 1*16384, bl_s + 1*128, xa, 0,
                                      nullptr, nullptr, nullptr, nullptr);
    k_gate<<<cdiv(NN,256),256,0,stream>>>(xa, gate_w + 2*DD, gate_b, 2, gbuf, NN);
    k_smstats<<<1,1024,0,stream>>>(gbuf, invp);
    k_wsum<<<BPG,128,0,stream>>>(xa, gbuf, invp, ro, 0, 256);

    // ================= stage 2 (chunked over pathways) =================
    for (int c = 0; c < NCH; ++c) {
        const int* ssrc = seidx + (size_t)c * CH_E;
        const int* sdst = seidx + ES_TOT + (size_t)c * CH_E;
        int nbase = c * CH_N;

        k_fill<<<cdiv(CH_N,256),256,0,stream>>>(nal, 1.0f, CH_N);
        k_fill<<<cdiv(CH_E,256),256,0,stream>>>(eal, 1.0f, CH_E);

        for (int layer = 0; layer < 3; ++layer) {
            const float* Wl = Wl_s + (2 + layer) * 16384;
            const float* Wr = Wr_s + (2 + layer) * 16384;
            const float* bl = bl_s + (2 + layer) * 128;
            int kkeep = (layer == 0) ? KK1 : (layer == 1) ? KK2 : KK3;
            int gi = 3 + layer;

            hipMemsetAsync(AGGc, 0, (size_t)CH_N * DD * sizeof(float), stream);
            hipMemsetAsync(deg2, 0, (size_t)CH_N * sizeof(float), stream);
            k_deg<<<cdiv(CH_E,256),256,0,stream>>>(sdst, eal, deg2, CH_E, nbase);
            if (layer == 0) {
                k_agg<<<cdiv((long long)CH_E*DD,256),256,0,stream>>>(ssrc, sdst, xa, eal, AGGc, CH_E, 7, 1, nbase);
                k_sage_v2<<<CH_N/64,256,0,stream>>>(xa, AGGc, deg2, Wl, Wr, bl, Xc, 1,
                                                    p_wrel + layer*DD, p_wroot + layer*DD, tbuf, rootd);
            } else {
                k_agg<<<cdiv((long long)CH_E*DD,256),256,0,stream>>>(ssrc, sdst, Xc, eal, AGGc, CH_E, 7, 0, nbase);
                k_sage_v2<<<CH_N/64,256,0,stream>>>(Xc, AGGc, deg2, Wl, Wr, bl, Xc, 0,
                                                    p_wrel + layer*DD, p_wroot + layer*DD, tbuf, rootd);
            }

            // SAGPool score: sagg = segsum(t[src]*w); topk adds brel + rootd
            hipMemsetAsync(sagg, 0, (size_t)CH_N * sizeof(float), stream);
            k_scoreagg<<<cdiv(CH_E,256),256,0,stream>>>(ssrc, sdst, tbuf, eal, sagg, CH_E, nbase);
            k_topk<<<CH_P,256,0,stream>>>(sagg, rootd, p_brel, layer, nal, kkeep);
            k_maskgate<<<CH_N/4,256,0,stream>>>(Xc, sagg, nal, gate_w + gi*DD, gate_b, gi, gbuf);
            k_ealive<<<cdiv(CH_E,256),256,0,stream>>>(ssrc, sdst, nal, eal, CH_E, nbase);
            k_smstats<<<CH_P,1024,0,stream>>>(gbuf, invp);
            k_wsum<<<CH_P*BPG,128,0,stream>>>(Xc, gbuf, invp, ro, 1 + c*CH_P, layer*128);
        }
    }

    // ================= head =================
    k_head<<<1,64,0,stream>>>(ro, lin_w, lin_b, m1w, m1b, m2w, m2b, m3w, m3b, out);
}